// Round 10
// baseline (98.628 us; speedup 1.0000x reference)
//
#include <hip/hip_runtime.h>
#include <math.h>

#define BB    8
#define TDIM  64
#define NN    128
#define DD    128
#define TTOUT 62      // T-2
#define W3    384     // 3*N

typedef __attribute__((ext_vector_type(8))) short bf16x8;
typedef __attribute__((ext_vector_type(4))) float f32x4;

__device__ __forceinline__ float sigf(float x){ return 1.0f/(1.0f+__expf(-x)); }
__device__ __forceinline__ unsigned short f2bf(float x){
  union{float f; unsigned u;} v; v.f=x;
  unsigned r = v.u + 0x7FFFu + ((v.u>>16)&1u);   // RNE
  return (unsigned short)(r>>16);
}
// XOR-swizzled ushort indices (T2/G4: spreads fragment rows across bank groups).
// 128-wide tiles (256B rows): granule=16B, 8 granules XOR'd by row&7 -> 2-way reads.
__device__ __forceinline__ int swzA(int row, int col){ return row*128 + (col ^ ((row&7)<<3)); }
// 64-wide tiles (128B rows): same 3-bit swizzle (cols < 64).
__device__ __forceinline__ int swzF(int row, int col){ return row*64  + (col ^ ((row&7)<<3)); }

// K_pre: blocks 0..511: rscale + ssum (column-pass, no shuffle storm).
//        blocks 512/513: W1/W2 -> transposed bf16.
__global__ __launch_bounds__(512) void k_pre(const float* __restrict__ feat,
    const float* __restrict__ w, const float* __restrict__ W1, const float* __restrict__ W2,
    float* __restrict__ rscale, float* __restrict__ ssum,
    unsigned short* __restrict__ W1T, unsigned short* __restrict__ W2T){
  __shared__ float sSig[DD];
  __shared__ float sRs[NN];
  __shared__ float sPart[4*DD];
  const int bid = blockIdx.x, tid = threadIdx.x;
  if(bid >= BB*TDIM){
    const float* W = (bid == BB*TDIM) ? W1 : W2;
    unsigned short* WT = (bid == BB*TDIM) ? W1T : W2T;
    for(int e=tid; e<DD*DD; e+=512){
      int k = e>>7, n = e&127;
      WT[n*DD + k] = f2bf(W[(size_t)k*DD + n]);
    }
    return;
  }
  const int bt = bid;
  if(tid < DD) sSig[tid] = sigf(w[tid]);
  __syncthreads();
  // phase A: rscale (row norms of G = feat*sig), 4 threads/row
  const int row = tid >> 2, q = tid & 3;
  const float* fp = feat + ((size_t)bt*NN + row)*DD + q*32;
  float ss = 0.f;
  #pragma unroll
  for(int i=0;i<8;i++){
    float4 v = *(const float4*)(fp + i*4);
    float g0 = v.x*sSig[q*32+i*4+0], g1 = v.y*sSig[q*32+i*4+1];
    float g2 = v.z*sSig[q*32+i*4+2], g3 = v.w*sSig[q*32+i*4+3];
    ss += g0*g0 + g1*g1 + g2*g2 + g3*g3;
  }
  ss += __shfl_xor(ss,1); ss += __shfl_xor(ss,2);
  float rs = 1.0f / fmaxf(sqrtf(ss), 1e-12f);
  if(q==0){ rscale[(size_t)bt*NN + row] = rs; sRs[row] = rs; }
  __syncthreads();
  // phase B: ssum[d] = sig[d] * sum_n feat[n][d]*rs[n]  (coalesced column pass, L1/L2-hot)
  const int d = tid & 127, rg = tid >> 7;
  const float* fc = feat + ((size_t)bt*NN + rg*32)*DD + d;
  float acc = 0.f;
  #pragma unroll 8
  for(int i=0;i<32;i++) acc += fc[(size_t)i*DD] * sRs[rg*32+i];
  sPart[rg*DD + d] = acc;
  __syncthreads();
  if(tid < DD)
    ssum[(size_t)bt*DD + tid] =
      (sPart[tid] + sPart[DD+tid] + sPart[2*DD+tid] + sPart[3*DD+tid]) * sSig[tid];
}

// K_dis: dis[b,tt,j] = deg>0 ? rsqrt(max(deg,1e-38)) : 0   (+ XCD swizzle)
__global__ void k_dis(const float* __restrict__ feat, const float* __restrict__ w,
                      const float* __restrict__ rscale, const float* __restrict__ ssum,
                      float* __restrict__ dis){
  __shared__ float s3[DD];
  __shared__ float sg[DD];
  int bt2 = (blockIdx.x & 7)*62 + (blockIdx.x >> 3);   // XCD-chunked: batch panel per XCD L2
  int b = bt2 / TTOUT, tt = bt2 % TTOUT;
  int tid = threadIdx.x;
  if(tid < DD){
    int base = (b*TDIM + tt)*DD;
    s3[tid] = ssum[base+tid] + ssum[base+DD+tid] + ssum[base+2*DD+tid];
    sg[tid] = sigf(w[tid]);
  }
  __syncthreads();
  int gr = (b*TDIM + tt)*NN + tid;
  const float4* fr = (const float4*)(feat + (size_t)gr*DD);
  float deg = 0.f;
  #pragma unroll 8
  for(int q=0;q<DD/4;q++){
    float4 f = fr[q];
    deg += f.x*sg[q*4+0]*s3[q*4+0] + f.y*sg[q*4+1]*s3[q*4+1]
         + f.z*sg[q*4+2]*s3[q*4+2] + f.w*sg[q*4+3]*s3[q*4+3];
  }
  deg *= rscale[gr];
  dis[(size_t)bt2*W3 + tid] = (deg > 0.f) ? rsqrtf(fmaxf(deg, 1e-38f)) : 0.f;
}

// K_main: round-9 structure, identical math/barriers; LDS re-laid-out with XOR swizzle
// (unpadded tiles), removing the 8-way bank conflicts on every MFMA fragment read.
__global__ __launch_bounds__(512,4) void k_main(
    const float* __restrict__ feat,
    const float* __restrict__ w,
    const float* __restrict__ rscale, const float* __restrict__ dis,
    const unsigned short* __restrict__ W1T, const float* __restrict__ b1,
    const unsigned short* __restrict__ W2T, const float* __restrict__ b2,
    const float* __restrict__ gamma, const float* __restrict__ beta,
    float* __restrict__ out)
{
  // ushort offsets: sA @0 (128x128), sG @16384 (32x128), sFt @20480 (128x64),
  // sP @28672 (128x64). FFN overlay: ovl=sA @0, sWt @16384 (128x64).
  __shared__ __align__(16) unsigned short sm[36864];   // 73,728 B
  __shared__ float sSig[DD];
  unsigned short* sA  = sm;
  unsigned short* sG  = sm + 16384;
  unsigned short* sFt = sm + 20480;
  unsigned short* sP  = sm + 28672;
  unsigned short* sWt = sm + 16384;

  const int tid = threadIdx.x;
  const int bid = blockIdx.x;
  const int bt2 = (bid & 7)*62 + (bid >> 3);   // XCD-chunked swizzle
  const int rowBase = (bt2/TTOUT)*TDIM*NN + (bt2%TTOUT)*NN;
  const float* disP = dis + (size_t)bt2*W3;

  const int lane = tid & 63, wid = tid >> 6;
  const int l15 = lane & 15, l4 = lane >> 4;
  const int m0 = wid * 16;

  if(tid < DD) sSig[tid] = sigf(w[tid]);
  __syncthreads();

  // prologue: sA = scaled GhL (window rows 256..383) in bf16
  #pragma unroll
  for(int e0=0; e0<8; ++e0){
    int e = e0*512 + tid;
    int d = e & 127, r0 = (e>>7)*4;
    float sg = sSig[d];
    #pragma unroll
    for(int i=0;i<4;i++){
      int j = 256 + r0 + i, gr = rowBase + j;
      float f = feat[(size_t)gr*DD + d];
      float fac = rscale[gr]*disP[j];
      sA[swzA(r0+i, d)] = f2bf(f*sg*fac);
    }
  }

  f32x4 acc2[8];
  #pragma unroll
  for(int i=0;i<8;i++) acc2[i] = (f32x4){0.f,0.f,0.f,0.f};

  for(int c=0; c<12; ++c){
    const int n0 = c*32;
    __syncthreads();   // prev phase2 done with sG/sFt/sP
    // stage sG (scaled bf16, row-major) + sFt (raw bf16, transposed [d][n])
    #pragma unroll
    for(int e0=0; e0<2; ++e0){
      int e = e0*512 + tid;
      int d = e & 127, r0 = (e>>7)*4;
      float sg = sSig[d];
      unsigned short fb[4];
      #pragma unroll
      for(int i=0;i<4;i++){
        int j = n0 + r0 + i, gr = rowBase + j;
        float f = feat[(size_t)gr*DD + d];
        float fac = rscale[gr]*disP[j];
        fb[i] = f2bf(f);
        sG[swzA(r0+i, d)] = f2bf(f*sg*fac);
      }
      unsigned int* fp = (unsigned int*)&sFt[swzF(d, r0)];   // r0%4==0; XOR hits bits>=3
      fp[0] = (unsigned)fb[0] | ((unsigned)fb[1]<<16);
      fp[1] = (unsigned)fb[2] | ((unsigned)fb[3]<<16);
    }
    __syncthreads();

    // phase1: P[:, n0:n0+32] = GhL(128xK=128) x Gtile^T
    f32x4 p0 = {0.f,0.f,0.f,0.f}, p1 = {0.f,0.f,0.f,0.f};
    #pragma unroll
    for(int ks=0; ks<4; ++ks){
      bf16x8 aA  = *(const bf16x8*)&sA[swzA(m0+l15, ks*32 + l4*8)];
      bf16x8 bg0 = *(const bf16x8*)&sG[swzA( 0+l15, ks*32 + l4*8)];
      bf16x8 bg1 = *(const bf16x8*)&sG[swzA(16+l15, ks*32 + l4*8)];
      p0 = __builtin_amdgcn_mfma_f32_16x16x32_bf16(aA, bg0, p0, 0,0,0);
      p1 = __builtin_amdgcn_mfma_f32_16x16x32_bf16(aA, bg1, p1, 0,0,0);
    }
    #pragma unroll
    for(int r=0;r<4;r++){
      sP[swzF(m0 + l4*4 + r,  0 + l15)] = f2bf(p0[r]);
      sP[swzF(m0 + l4*4 + r, 16 + l15)] = f2bf(p1[r]);
    }
    __syncthreads();

    // phase2: agg += P(128x32) x F(32x128)
    bf16x8 aP = *(const bf16x8*)&sP[swzF(m0+l15, l4*8)];
    #pragma unroll
    for(int dt=0; dt<8; ++dt){
      bf16x8 bF = *(const bf16x8*)&sFt[swzF(dt*16+l15, l4*8)];
      acc2[dt] = __builtin_amdgcn_mfma_f32_16x16x32_bf16(aP, bF, acc2[dt], 0,0,0);
    }
  }

  // agg -> ovl (bf16); strip-local
  unsigned short* ovl = sA;
  #pragma unroll
  for(int dt=0; dt<8; ++dt)
    #pragma unroll
    for(int r=0;r<4;r++)
      ovl[swzA(m0+l4*4+r, dt*16+l15)] = f2bf(acc2[dt][r]);

  // GEMM1: h = relu(agg @ W1 + b1)
  f32x4 acch[8];
  #pragma unroll
  for(int dt=0; dt<8; ++dt){
    float bv = b1[dt*16+l15];
    acch[dt] = (f32x4){bv,bv,bv,bv};
  }
  for(int kh=0; kh<2; ++kh){
    __syncthreads();   // all reads of sG/sFt/sP (or prev sWt) done
    #pragma unroll
    for(int it=0; it<2; ++it){
      int e = it*512 + tid, n = e>>3, sg2 = e&7;
      uint4 v = *(const uint4*)(W1T + (size_t)n*DD + kh*64 + sg2*8);
      *(uint4*)&sWt[swzF(n, sg2*8)] = v;
    }
    __syncthreads();
    #pragma unroll
    for(int ks=0; ks<2; ++ks){
      bf16x8 aA = *(const bf16x8*)&ovl[swzA(m0+l15, kh*64 + ks*32 + l4*8)];
      #pragma unroll
      for(int dt=0; dt<8; ++dt){
        bf16x8 bW = *(const bf16x8*)&sWt[swzF(dt*16+l15, ks*32 + l4*8)];
        acch[dt] = __builtin_amdgcn_mfma_f32_16x16x32_bf16(aA, bW, acch[dt], 0,0,0);
      }
    }
  }
  __syncthreads();
  // h -> ovl (strip-local)
  #pragma unroll
  for(int dt=0; dt<8; ++dt)
    #pragma unroll
    for(int r=0;r<4;r++)
      ovl[swzA(m0+l4*4+r, dt*16+l15)] = f2bf(fmaxf(acch[dt][r], 0.f));

  // GEMM2: o = h @ W2 + b2
  f32x4 acco[8];
  #pragma unroll
  for(int dt=0; dt<8; ++dt){
    float bv = b2[dt*16+l15];
    acco[dt] = (f32x4){bv,bv,bv,bv};
  }
  for(int kh=0; kh<2; ++kh){
    __syncthreads();
    #pragma unroll
    for(int it=0; it<2; ++it){
      int e = it*512 + tid, n = e>>3, sg2 = e&7;
      uint4 v = *(const uint4*)(W2T + (size_t)n*DD + kh*64 + sg2*8);
      *(uint4*)&sWt[swzF(n, sg2*8)] = v;
    }
    __syncthreads();
    #pragma unroll
    for(int ks=0; ks<2; ++ks){
      bf16x8 aA = *(const bf16x8*)&ovl[swzA(m0+l15, kh*64 + ks*32 + l4*8)];
      #pragma unroll
      for(int dt=0; dt<8; ++dt){
        bf16x8 bW = *(const bf16x8*)&sWt[swzF(dt*16+l15, ks*32 + l4*8)];
        acco[dt] = __builtin_amdgcn_mfma_f32_16x16x32_bf16(aA, bW, acco[dt], 0,0,0);
      }
    }
  }

  // residual + LayerNorm (fp32)
  const float* fres = feat + (size_t)(rowBase + 256)*DD;
  #pragma unroll
  for(int r=0;r<4;r++){
    int m = m0 + l4*4 + r;
    float vals[8]; float s1 = 0.f, s2 = 0.f;
    #pragma unroll
    for(int dt=0; dt<8; ++dt){
      int d = dt*16 + l15;
      float v = acco[dt][r] + fres[(size_t)m*DD + d];
      vals[dt] = v; s1 += v; s2 += v*v;
    }
    #pragma unroll
    for(int k=1;k<16;k<<=1){ s1 += __shfl_xor(s1,k); s2 += __shfl_xor(s2,k); }
    float mu   = s1*(1.0f/DD);
    float rstd = rsqrtf(s2*(1.0f/DD) - mu*mu + 1e-5f);
    #pragma unroll
    for(int dt=0; dt<8; ++dt){
      int d = dt*16 + l15;
      out[((size_t)bt2*NN + m)*DD + d] = (vals[dt]-mu)*rstd*gamma[d] + beta[d];
    }
  }
}

extern "C" void kernel_launch(void* const* d_in, const int* in_sizes, int n_in,
                              void* d_out, int out_size, void* d_ws, size_t ws_size,
                              hipStream_t stream){
  const float* feat  = (const float*)d_in[0];
  const float* w     = (const float*)d_in[1];
  const float* W1    = (const float*)d_in[2];
  const float* b1    = (const float*)d_in[3];
  const float* W2    = (const float*)d_in[4];
  const float* b2    = (const float*)d_in[5];
  const float* gamma = (const float*)d_in[6];
  const float* beta  = (const float*)d_in[7];
  float* out = (float*)d_out;

  char* ws = (char*)d_ws;
  float* rscale = (float*)(ws + 0);                       // 262,144 B
  float* ssum   = (float*)(ws + 262144);                  // 262,144 B
  float* dis    = (float*)(ws + 524288);                  // 761,856 B
  unsigned short* W1T = (unsigned short*)(ws + 1286144);  // 32,768 B
  unsigned short* W2T = (unsigned short*)(ws + 1318912);  // 32,768 B

  k_pre<<<BB*TDIM + 2, 512, 0, stream>>>(feat, w, W1, W2, rscale, ssum, W1T, W2T);
  k_dis<<<BB*TTOUT, W3, 0, stream>>>(feat, w, rscale, ssum, dis);
  k_main<<<BB*TTOUT, 512, 0, stream>>>(feat, w, rscale, dis, W1T, b1, W2T, b2,
                                       gamma, beta, out);
}